// Round 4
// baseline (921.712 us; speedup 1.0000x reference)
//
#include <hip/hip_runtime.h>
#include <hip/hip_fp16.h>

typedef _Float16 h2v __attribute__((ext_vector_type(2)));
typedef _Float16 f16x8 __attribute__((ext_vector_type(8)));
typedef float f32x4 __attribute__((ext_vector_type(4)));
typedef unsigned int u32;
typedef unsigned short u16;

#define NB 256
#define NP 512
#define NH 256

// ws layout in dwords
// WH: Wh B-frags. dword F = (((w*48 + f)*64 + l)*4 + d)
//   f = t*8 + kt; t = g*2 + c (g=gate 0..2, c=col-half 0..1), kt = K-tile 0..7
//   k = kt*32 + (l>>4)*8 + 2d (+1 for hi half), col = g*256 + w*32 + c*16 + (l&15)
#define OFF_WH 0
#define LEN_WH 98304            // 8 waves * 48 frags * 64 lanes * 4 dwords
// WIB: Wi B-frags (K=32, single K-tile, rows >=17 zero-padded)
//   dword F-OFF = ((w*6 + t)*64 + l)*4 + d ; k = (l>>4)*8 + 2d ; col as above
#define OFF_WIB (OFF_WH + LEN_WH)      // 98304
#define LEN_WIB 12288           // 8 * 6 * 64 * 4
#define OFF_W1 (OFF_WIB + LEN_WIB)     // 110592
#define LEN_W1 68096            // 2 * 133 * 256
#define OFF_W2 (OFF_W1 + LEN_W1)       // 178688
#define LEN_W2 65536            // 2 * 128 * 256
#define OFF_W3 (OFF_W2 + LEN_W2)       // 244224
#define LEN_W3 256              // 2 * 128
#define WS_DWORDS (OFF_W3 + LEN_W3)    // 244480 dwords

__device__ __forceinline__ u32 pack2(float lo, float hi) {
    h2v v; v.x = (_Float16)lo; v.y = (_Float16)hi;
    return __builtin_bit_cast(u32, v);
}

__device__ __forceinline__ float fdot2(u32 a, u32 b, float c) {
#if __has_builtin(__builtin_amdgcn_fdot2)
    return __builtin_amdgcn_fdot2(__builtin_bit_cast(h2v, a),
                                  __builtin_bit_cast(h2v, b), c, false);
#else
    h2v x = __builtin_bit_cast(h2v, a), y = __builtin_bit_cast(h2v, b);
    return c + (float)x.x * (float)y.x + (float)x.y * (float)y.y;
#endif
}

// ---------------- pack kernel ----------------
__global__ __launch_bounds__(256) void pack_kernel(
    const float* __restrict__ Wi, const float* __restrict__ Whrz,
    const float* __restrict__ Whn, const float* __restrict__ W1,
    const float* __restrict__ W2, const float* __restrict__ W3,
    u32* __restrict__ ws)
{
    for (int F = blockIdx.x * 256 + threadIdx.x; F < WS_DWORDS; F += gridDim.x * 256) {
        u32 val;
        if (F < OFF_WIB) {
            int d = F & 3; int r = F >> 2;
            int l = r & 63; int q = r >> 6;      // q = w*48 + f
            int f = q % 48; int w = q / 48;
            int t = f >> 3; int kt = f & 7;
            int g = t >> 1, c = t & 1;
            int k = kt * 32 + ((l >> 4) << 3) + 2 * d;
            int col = g * 256 + w * 32 + c * 16 + (l & 15);
            float lo, hi;
            if (col < 512) { lo = Whrz[k * 512 + col]; hi = Whrz[(k + 1) * 512 + col]; }
            else { lo = Whn[k * 256 + (col - 512)]; hi = Whn[(k + 1) * 256 + (col - 512)]; }
            val = pack2(lo, hi);
        } else if (F < OFF_W1) {
            int j = F - OFF_WIB;
            int d = j & 3; int r = j >> 2;
            int l = r & 63; int q = r >> 6;      // q = w*6 + t
            int t = q % 6; int w = q / 6;
            int g = t >> 1, c = t & 1;
            int k = ((l >> 4) << 3) + 2 * d;
            int col = g * 256 + w * 32 + c * 16 + (l & 15);
            float lo = (k < 17) ? Wi[k * 768 + col] : 0.f;
            float hi = (k + 1 < 17) ? Wi[(k + 1) * 768 + col] : 0.f;
            val = pack2(lo, hi);
        } else if (F < OFF_W2) {
            int j = F - OFF_W1; int c = j / (133 * 256); int r = j % (133 * 256);
            int kk = r >> 8; int o = r & 255;
            int k = 2 * kk;
            float lo = W1[(c * 265 + k) * 256 + o];
            float hi = (k + 1 < 265) ? W1[(c * 265 + k + 1) * 256 + o] : 0.f;
            val = pack2(lo, hi);
        } else if (F < OFF_W3) {
            int j = F - OFF_W2; int c = j >> 15; int r = j & 32767;
            int kk = r >> 8; int o = r & 255;
            float lo = W2[(c * 256 + 2 * kk) * 256 + o];
            float hi = W2[(c * 256 + 2 * kk + 1) * 256 + o];
            val = pack2(lo, hi);
        } else {
            int j = F - OFF_W3; int c = j >> 7; int jj = j & 127;
            float lo = W3[c * 256 + 2 * jj];
            float hi = W3[c * 256 + 2 * jj + 1];
            val = pack2(lo, hi);
        }
        ws[F] = val;
    }
}

// One asm MFMA with B sourced DIRECTLY from AGPR (no accvgpr moves).
#define MFMA_A(acc, hv, bf) \
    asm volatile("v_mfma_f32_16x16x32_f16 %0, %1, %2, %0" \
                 : "+a"(acc) : "v"(hv), "a"(bf))

// ---------------- main kernel: one batch row per workgroup --------------
// h@Wh on the MFMA pipe with weights resident in AGPRs, read natively by
// v_mfma via inline asm "a" constraints (the HIP intrinsic path inserts a
// v_accvgpr_read per operand dword -> ~770 wasted VALU cyc/step, measured
// rounds -1..3). 2 passes x 3 gate-tiles x 8 chained K-tiles; gates fully
// in-register; one barrier/step; x@Wi precomputed 16 steps at a time.
__global__ __launch_bounds__(512, 2) void qnet_kernel(
    const float* __restrict__ particles, const float* __restrict__ pweights,
    const float* __restrict__ actions, const float* __restrict__ timev,
    const float* __restrict__ bi, const float* __restrict__ bn,
    const float* __restrict__ b1, const float* __restrict__ b2,
    const float* __restrict__ b3, const int* __restrict__ nts,
    const u32* __restrict__ ws, float* __restrict__ out)
{
    __shared__ __align__(16) u32 sX[NP * 16];      // 32768 B
    __shared__ __align__(16) float sG[8 * 1536];   // 49152 B
    __shared__ __align__(16) u16 sH2[2][NH];       // 1024 B
    __shared__ __align__(16) float sHf[NH];        // 1024 B
    __shared__ __align__(16) float sMisc[16];      // 64 B

    const int b = blockIdx.x;
    const int tid = threadIdx.x;
    const int lane = tid & 63;
    const int wid = tid >> 6;   // 0..7

    // ---- Wh B-frags -> AGPRs (192 regs), consumed only by asm "a" ----
    f16x8 bfh[48];
    {
        const uint4* gp = (const uint4*)(ws + OFF_WH) + (wid * 48) * 64 + lane;
        #pragma unroll
        for (int i = 0; i < 48; ++i) bfh[i] = __builtin_bit_cast(f16x8, gp[i * 64]);
    }
    // ---- stage x rows as fp16 pairs, padded to 16 pairs (K=32 halves) ----
    {
        const float2* pr2 = (const float2*)(particles + (long)b * NP * 16);
        for (int j = tid; j < NP * 8; j += 512) {
            int p = j >> 3, q = j & 7;
            float2 v = pr2[j];
            sX[p * 16 + q] = pack2(v.x, v.y);
        }
        const float* wr = pweights + (long)b * NP;
        for (int j = tid; j < NP * 8; j += 512) {
            int p = j >> 3, q = j & 7;
            sX[p * 16 + 8 + q] = (q == 0) ? pack2(wr[p], 0.f) : 0u;
        }
    }
    if (tid < 256) ((u32*)sH2)[tid] = 0u;
    if (tid < 8) sMisc[tid] = actions[b * 8 + tid];
    if (tid == 8) sMisc[8] = timev[b] / (float)nts[0];

    float birL = 0.f, bizL = 0.f, binnL = 0.f, bnnL = 0.f, hreg = 0.f;
    if (lane < 32) {
        int j = wid * 32 + lane;
        birL = bi[j]; bizL = bi[NH + j]; binnL = bi[2 * NH + j]; bnnL = bn[j];
    }
    __syncthreads();

    const uint4* wibp = (const uint4*)(ws + OFF_WIB) + (wid * 6) * 64 + lane;

    #pragma unroll 1
    for (int p = 0; p < NP; ++p) {
        if ((p & 15) == 0) {
            // ---- x@Wi for steps p..p+15 (intrinsic MFMA, pairwise) ----
            f16x8 av = __builtin_bit_cast(f16x8,
                ((const uint4*)sX)[(p + (lane & 15)) * 4 + (lane >> 4)]);
            f32x4 z4 = {0.f, 0.f, 0.f, 0.f};
            int sb = (lane >> 4) << 2;
            float* gw = sG + wid * 1536 + (lane & 15);
            {
                f32x4 g0 = __builtin_amdgcn_mfma_f32_16x16x32_f16(av, __builtin_bit_cast(f16x8, wibp[0 * 64]), z4, 0, 0, 0);
                f32x4 g1 = __builtin_amdgcn_mfma_f32_16x16x32_f16(av, __builtin_bit_cast(f16x8, wibp[1 * 64]), z4, 0, 0, 0);
                #pragma unroll
                for (int r = 0; r < 4; ++r) {
                    gw[(sb + r) * 32]      = g0[r];
                    gw[(sb + r) * 32 + 16] = g1[r];
                }
            }
            {
                f32x4 g2 = __builtin_amdgcn_mfma_f32_16x16x32_f16(av, __builtin_bit_cast(f16x8, wibp[2 * 64]), z4, 0, 0, 0);
                f32x4 g3 = __builtin_amdgcn_mfma_f32_16x16x32_f16(av, __builtin_bit_cast(f16x8, wibp[3 * 64]), z4, 0, 0, 0);
                #pragma unroll
                for (int r = 0; r < 4; ++r) {
                    gw[512 + (sb + r) * 32]      = g2[r];
                    gw[512 + (sb + r) * 32 + 16] = g3[r];
                }
            }
            {
                f32x4 g4 = __builtin_amdgcn_mfma_f32_16x16x32_f16(av, __builtin_bit_cast(f16x8, wibp[4 * 64]), z4, 0, 0, 0);
                f32x4 g5 = __builtin_amdgcn_mfma_f32_16x16x32_f16(av, __builtin_bit_cast(f16x8, wibp[5 * 64]), z4, 0, 0, 0);
                #pragma unroll
                for (int r = 0; r < 4; ++r) {
                    gw[1024 + (sb + r) * 32]      = g4[r];
                    gw[1024 + (sb + r) * 32 + 16] = g5[r];
                }
            }
            __syncthreads();
        }

        // ---- this step's x@Wi sums (independent of h, read early) ----
        float gR, gZ, gN;
        {
            const float* gp = sG + wid * 1536 + (p & 15) * 32 + (lane & 31);
            gR = gp[0]; gZ = gp[512]; gN = gp[1024];
        }

        const uint4* hbuf = (const uint4*)(&sH2[p & 1][0]);
        const int hq = lane >> 4;

        // ---- pass 0: col-half 0 tiles (g=0,1,2) ----
        float s0r, s0z, s0n, s1r, s1z, s1n;
        {
            f32x4 a0 = {0.f, 0.f, 0.f, 0.f}, a1 = a0, a2 = a0;
            asm volatile("s_nop 3" : "+a"(a0), "+a"(a1), "+a"(a2));
            #pragma unroll
            for (int kt = 0; kt < 8; ++kt) {
                f16x8 hv = __builtin_bit_cast(f16x8, hbuf[kt * 4 + hq]);
                MFMA_A(a0, hv, bfh[kt]);           // t0 = g0,c0
                MFMA_A(a1, hv, bfh[16 + kt]);      // t2 = g1,c0
                MFMA_A(a2, hv, bfh[32 + kt]);      // t4 = g2,c0
            }
            asm volatile("s_nop 7\n\ts_nop 7" : "+a"(a0), "+a"(a1), "+a"(a2));
            s0r = a0[0]; s0z = a1[0]; s0n = a2[0];
        }
        // ---- pass 1: col-half 1 tiles ----
        {
            f32x4 a0 = {0.f, 0.f, 0.f, 0.f}, a1 = a0, a2 = a0;
            asm volatile("s_nop 3" : "+a"(a0), "+a"(a1), "+a"(a2));
            #pragma unroll
            for (int kt = 0; kt < 8; ++kt) {
                f16x8 hv = __builtin_bit_cast(f16x8, hbuf[kt * 4 + hq]);
                MFMA_A(a0, hv, bfh[8 + kt]);       // t1 = g0,c1
                MFMA_A(a1, hv, bfh[24 + kt]);      // t3 = g1,c1
                MFMA_A(a2, hv, bfh[40 + kt]);      // t5 = g2,c1
            }
            asm volatile("s_nop 7\n\ts_nop 7" : "+a"(a0), "+a"(a1), "+a"(a2));
            s1r = a0[0]; s1z = a1[0]; s1n = a2[0];
        }

        // ---- gates fully in-register (lane l<32 owns h[wid*32+l]) ----
        bool hic = (lane & 16) != 0;
        float srm = hic ? s1r : s0r;
        float szm = hic ? s1z : s0z;
        float snm = hic ? s1n : s0n;
        if (lane < 32) {
            float xr = gR + birL + srm;
            float xz = gZ + bizL + szm;
            float xn = gN + binnL;
            float r = 1.f / (1.f + __expf(-xr));
            float z = 1.f / (1.f + __expf(-xz));
            float targ = xn + r * (snm + bnnL);
            float e2 = __expf(2.f * targ);
            float n = 1.f - 2.f / (e2 + 1.f);
            hreg = (1.f - z) * n + z * hreg;
            _Float16 hh = (_Float16)hreg;
            sH2[(p + 1) & 1][wid * 32 + lane] = __builtin_bit_cast(u16, hh);
        }
        __syncthreads();
    }

    // ---------------- MLP tail ----------------
    if (lane < 32) sHf[wid * 32 + lane] = hreg;
    __syncthreads();
    u32* sHid = (u32*)sG;             // 133 dwords
    u16* sL1 = (u16*)(sG + 512);      // 512 halves
    u16* sL2 = (u16*)(sG + 1024);     // 512 halves
    if (tid < 128) sHid[tid] = pack2(sHf[2 * tid], sHf[2 * tid + 1]);
    else if (tid < 132) { int i = tid - 128; sHid[tid] = pack2(sMisc[2 * i], sMisc[2 * i + 1]); }
    else if (tid == 132) sHid[132] = pack2(sMisc[8], 0.f);
    __syncthreads();
    // L1: 512 outputs (2 critics x 256)
    {
        int c = tid >> 8, o = tid & 255;
        float acc = b1[c * 256 + o];
        const u32* wp = ws + OFF_W1 + c * 133 * 256 + o;
        #pragma unroll 4
        for (int kk = 0; kk < 133; ++kk) acc = fdot2(wp[kk * 256], sHid[kk], acc);
        acc = fmaxf(acc, 0.f);
        _Float16 a16 = (_Float16)acc;
        sL1[tid] = __builtin_bit_cast(u16, a16);
    }
    __syncthreads();
    // L2
    {
        int c = tid >> 8, o = tid & 255;
        float acc = b2[c * 256 + o];
        const u32* wp = ws + OFF_W2 + c * 128 * 256 + o;
        const u32* hp = (const u32*)sL1 + c * 128;
        #pragma unroll 4
        for (int kk = 0; kk < 128; ++kk) acc = fdot2(wp[kk * 256], hp[kk], acc);
        acc = fmaxf(acc, 0.f);
        _Float16 a16 = (_Float16)acc;
        sL2[tid] = __builtin_bit_cast(u16, a16);
    }
    __syncthreads();
    // L3: 2 outputs via wave reduction
    if (tid < 128) {
        int c = tid >> 6, l = tid & 63;
        const u32* wp = ws + OFF_W3 + c * 128;
        const u32* hp = (const u32*)sL2 + c * 128;
        float acc = fdot2(wp[l], hp[l], 0.f);
        acc = fdot2(wp[64 + l], hp[64 + l], acc);
        #pragma unroll
        for (int off = 32; off > 0; off >>= 1) acc += __shfl_down(acc, off);
        if (l == 0) out[b * 2 + c] = acc + b3[c];
    }
}

extern "C" void kernel_launch(void* const* d_in, const int* in_sizes, int n_in,
                              void* d_out, int out_size, void* d_ws, size_t ws_size,
                              hipStream_t stream) {
    const float* particles = (const float*)d_in[0];
    const float* pweights  = (const float*)d_in[1];
    const float* actions   = (const float*)d_in[2];
    const float* timev     = (const float*)d_in[3];
    const float* Wi        = (const float*)d_in[4];
    const float* bi        = (const float*)d_in[5];
    const float* Whrz      = (const float*)d_in[6];
    const float* Whn       = (const float*)d_in[7];
    const float* bn        = (const float*)d_in[8];
    const float* W1        = (const float*)d_in[9];
    const float* b1        = (const float*)d_in[10];
    const float* W2        = (const float*)d_in[11];
    const float* b2        = (const float*)d_in[12];
    const float* W3        = (const float*)d_in[13];
    const float* b3        = (const float*)d_in[14];
    const int*   nts       = (const int*)d_in[15];
    u32* ws = (u32*)d_ws;
    float* outp = (float*)d_out;

    pack_kernel<<<(WS_DWORDS + 255) / 256, 256, 0, stream>>>(Wi, Whrz, Whn, W1, W2, W3, ws);
    qnet_kernel<<<NB, 512, 0, stream>>>(particles, pweights, actions, timev,
                                        bi, bn, b1, b2, b3, nts, ws, outp);
}

// Round 6
// 844.986 us; speedup vs baseline: 1.0908x; 1.0908x over previous
//
#include <hip/hip_runtime.h>
#include <hip/hip_fp16.h>

typedef _Float16 h2v __attribute__((ext_vector_type(2)));
typedef _Float16 f16x8 __attribute__((ext_vector_type(8)));
typedef float f32x4 __attribute__((ext_vector_type(4)));
typedef unsigned int u32;
typedef unsigned short u16;

#define NB 256
#define NP 512
#define NH 256
#define NT 1024     // threads per block (16 waves)

// ws layout in dwords
// WH: per-lane fdot2 weights, 16 waves. dword F = ((w*96 + i)*64 + l)
//   i = g*32 + t (g = gate 0..2, t = k-pair 0..31)
//   col = g*256 + w*16 + (l&15), k = (l>>4)*64 + 2t
//   halves = Wh[k][col], Wh[k+1][col]
#define OFF_WH 0
#define LEN_WH 98304            // 16 waves * 96 * 64 lanes
// WIB: Wi B-frags (K=32, one tile; rows >=17 zero-padded)
//   dword F-OFF = ((w*3 + g)*64 + l)*4 + d ; k = (l>>4)*8 + 2d
//   col = g*256 + w*16 + (l&15)
#define OFF_WIB (OFF_WH + LEN_WH)      // 98304
#define LEN_WIB 12288           // 16 * 3 * 64 * 4
#define OFF_W1 (OFF_WIB + LEN_WIB)     // 110592
#define LEN_W1 68096            // 2 * 133 * 256
#define OFF_W2 (OFF_W1 + LEN_W1)       // 178688
#define LEN_W2 65536            // 2 * 128 * 256
#define OFF_W3 (OFF_W2 + LEN_W2)       // 244224
#define LEN_W3 256              // 2 * 128
#define WS_DWORDS (OFF_W3 + LEN_W3)    // 244480 dwords

__device__ __forceinline__ u32 pack2(float lo, float hi) {
    h2v v; v.x = (_Float16)lo; v.y = (_Float16)hi;
    return __builtin_bit_cast(u32, v);
}

__device__ __forceinline__ float fdot2(u32 a, u32 b, float c) {
#if __has_builtin(__builtin_amdgcn_fdot2)
    return __builtin_amdgcn_fdot2(__builtin_bit_cast(h2v, a),
                                  __builtin_bit_cast(h2v, b), c, false);
#else
    h2v x = __builtin_bit_cast(h2v, a), y = __builtin_bit_cast(h2v, b);
    return c + (float)x.x * (float)y.x + (float)x.y * (float)y.y;
#endif
}

// ---------------- pack kernel ----------------
__global__ __launch_bounds__(256) void pack_kernel(
    const float* __restrict__ Wi, const float* __restrict__ Whrz,
    const float* __restrict__ Whn, const float* __restrict__ W1,
    const float* __restrict__ W2, const float* __restrict__ W3,
    u32* __restrict__ ws)
{
    for (int F = blockIdx.x * 256 + threadIdx.x; F < WS_DWORDS; F += gridDim.x * 256) {
        u32 val;
        if (F < OFF_WIB) {
            // per-lane fdot2 weight pack
            int l = F & 63; int t = F >> 6;
            int i = t % 96; int w = t / 96;        // w = 0..15
            int g = i >> 5; int tt = i & 31;
            int col = g * 256 + w * 16 + (l & 15);
            int k = ((l >> 4) << 6) + 2 * tt;      // quarter*64 + 2t
            float lo, hi;
            if (col < 512) { lo = Whrz[k * 512 + col]; hi = Whrz[(k + 1) * 512 + col]; }
            else { lo = Whn[k * 256 + (col - 512)]; hi = Whn[(k + 1) * 256 + (col - 512)]; }
            val = pack2(lo, hi);
        } else if (F < OFF_W1) {
            int j = F - OFF_WIB;
            int d = j & 3; int r = j >> 2;
            int l = r & 63; int q2 = r >> 6;       // q2 = w*3 + g
            int g = q2 % 3; int w = q2 / 3;
            int k = ((l >> 4) << 3) + 2 * d;
            int col = g * 256 + w * 16 + (l & 15);
            float lo = (k < 17) ? Wi[k * 768 + col] : 0.f;
            float hi = (k + 1 < 17) ? Wi[(k + 1) * 768 + col] : 0.f;
            val = pack2(lo, hi);
        } else if (F < OFF_W2) {
            int j = F - OFF_W1; int c = j / (133 * 256); int r = j % (133 * 256);
            int kk = r >> 8; int o = r & 255;
            int k = 2 * kk;
            float lo = W1[(c * 265 + k) * 256 + o];
            float hi = (k + 1 < 265) ? W1[(c * 265 + k + 1) * 256 + o] : 0.f;
            val = pack2(lo, hi);
        } else if (F < OFF_W3) {
            int j = F - OFF_W2; int c = j >> 15; int r = j & 32767;
            int kk = r >> 8; int o = r & 255;
            float lo = W2[(c * 256 + 2 * kk) * 256 + o];
            float hi = W2[(c * 256 + 2 * kk + 1) * 256 + o];
            val = pack2(lo, hi);
        } else {
            int j = F - OFF_W3; int c = j >> 7; int jj = j & 127;
            float lo = W3[c * 256 + 2 * jj];
            float hi = W3[c * 256 + 2 * jj + 1];
            val = pack2(lo, hi);
        }
        ws[F] = val;
    }
}

// ---------------- main kernel: one batch row per workgroup --------------
// h@Wh on the VALU (v_dot2), 16 waves: lane l of wave w owns the r,z,n
// columns of h-index w*16+(l&15) over K-quarter (l>>4). 96 fdot2/lane/step,
// 96 weight dwords/lane. 1024-thread block caps VGPR at 128/lane (4 w/SIMD):
// scan live set ~96+25 fits; Wi B-frags deliberately NOT held in registers
// (reloaded from L2 each 16-step chunk) to stay under the cap.
// Quarters reduce via shfl_xor(16),(32); gates in-register; 1 barrier/step.
__global__ __launch_bounds__(1024, 4) void qnet_kernel(
    const float* __restrict__ particles, const float* __restrict__ pweights,
    const float* __restrict__ actions, const float* __restrict__ timev,
    const float* __restrict__ bi, const float* __restrict__ bn,
    const float* __restrict__ b1, const float* __restrict__ b2,
    const float* __restrict__ b3, const int* __restrict__ nts,
    const u32* __restrict__ ws, float* __restrict__ out)
{
    __shared__ __align__(16) u32 sX[NP * 16];      // 32768 B
    __shared__ __align__(16) float sG[16 * 768];   // 49152 B, x@Wi chunk
    __shared__ __align__(16) u32 sH2[2][144];      // 1152 B, h fp16 pairs,
                                                   // 4 quarters x 36 dwords (pad 4)
    __shared__ __align__(16) float sHf[NH];        // 1024 B
    __shared__ __align__(16) float sMisc[16];      // 64 B

    const int b = blockIdx.x;
    const int tid = threadIdx.x;
    const int lane = tid & 63;
    const int wid = tid >> 6;   // 0..15

    // ---- Wh fdot2 weights into 96 VGPRs (coalesced, stride-64) ----
    u32 wreg[96];
    {
        const u32* gp = ws + OFF_WH + (wid * 96) * 64 + lane;
        #pragma unroll
        for (int i = 0; i < 96; ++i) wreg[i] = gp[i * 64];
    }
    // ---- stage x rows as fp16 pairs, padded to 16 pairs (K=32 halves) ----
    {
        const float2* pr2 = (const float2*)(particles + (long)b * NP * 16);
        for (int j = tid; j < NP * 8; j += NT) {
            int p = j >> 3, q = j & 7;
            float2 v = pr2[j];
            sX[p * 16 + q] = pack2(v.x, v.y);
        }
        const float* wr = pweights + (long)b * NP;
        for (int j = tid; j < NP * 8; j += NT) {
            int p = j >> 3, q = j & 7;
            sX[p * 16 + 8 + q] = (q == 0) ? pack2(wr[p], 0.f) : 0u;
        }
    }
    if (tid < 288) ((u32*)sH2)[tid] = 0u;
    if (tid < 8) sMisc[tid] = actions[b * 8 + tid];
    if (tid == 8) sMisc[8] = timev[b] / (float)nts[0];

    // ---- per-lane gate biases (lane l<16 owns h-index wid*16+l) ----
    float birL = 0.f, bizL = 0.f, binnL = 0.f, bnnL = 0.f, hreg = 0.f;
    if (lane < 16) {
        int j = wid * 16 + lane;
        birL = bi[j]; bizL = bi[NH + j]; binnL = bi[2 * NH + j]; bnnL = bn[j];
    }
    __syncthreads();

    const int hq4 = (lane >> 4) * 9;    // uint4 base of this lane's K-quarter
    const uint4* wibp = (const uint4*)(ws + OFF_WIB) + (wid * 3) * 64 + lane;

    #pragma unroll 1
    for (int p = 0; p < NP; ++p) {
        if ((p & 15) == 0) {
            // ---- x@Wi for steps p..p+15: rows = steps, one K-tile ----
            // Wi B-frags reloaded from L2 each chunk (not register-resident)
            f16x8 av = __builtin_bit_cast(f16x8,
                ((const uint4*)sX)[(p + (lane & 15)) * 4 + (lane >> 4)]);
            f32x4 z4 = {0.f, 0.f, 0.f, 0.f};
            int sb = (lane >> 4) << 2;
            float* gw = sG + wid * 768 + (lane & 15);
            {
                f16x8 wib0 = __builtin_bit_cast(f16x8, wibp[0]);
                f32x4 g0 = __builtin_amdgcn_mfma_f32_16x16x32_f16(av, wib0, z4, 0, 0, 0);
                #pragma unroll
                for (int r = 0; r < 4; ++r) gw[(sb + r) * 16] = g0[r];
            }
            {
                f16x8 wib1 = __builtin_bit_cast(f16x8, wibp[64]);
                f32x4 g1 = __builtin_amdgcn_mfma_f32_16x16x32_f16(av, wib1, z4, 0, 0, 0);
                #pragma unroll
                for (int r = 0; r < 4; ++r) gw[256 + (sb + r) * 16] = g1[r];
            }
            {
                f16x8 wib2 = __builtin_bit_cast(f16x8, wibp[128]);
                f32x4 g2 = __builtin_amdgcn_mfma_f32_16x16x32_f16(av, wib2, z4, 0, 0, 0);
                #pragma unroll
                for (int r = 0; r < 4; ++r) gw[512 + (sb + r) * 16] = g2[r];
            }
            __syncthreads();
        }

        // ---- this step's x@Wi sums (independent of h, read early) ----
        float gR, gZ, gN;
        {
            const float* gp = sG + wid * 768 + (p & 15) * 16 + (lane & 15);
            gR = gp[0]; gZ = gp[256]; gN = gp[512];
        }

        // ---- h@Wh on the VALU: 3 cols x 32 k-pairs per lane ----
        const uint4* hb = (const uint4*)(&sH2[p & 1][0]);
        float aR = 0.f, aZ = 0.f, aN = 0.f;
        #pragma unroll
        for (int c = 0; c < 8; ++c) {
            uint4 hvv = hb[hq4 + c];
            u32 hv[4] = {hvv.x, hvv.y, hvv.z, hvv.w};
            #pragma unroll
            for (int j = 0; j < 4; ++j) {
                int t = c * 4 + j;
                aR = fdot2(wreg[t],      hv[j], aR);
                aZ = fdot2(wreg[32 + t], hv[j], aZ);
                aN = fdot2(wreg[64 + t], hv[j], aN);
            }
        }
        // ---- K-quarter reduce in-wave ----
        aR += __shfl_xor(aR, 16); aR += __shfl_xor(aR, 32);
        aZ += __shfl_xor(aZ, 16); aZ += __shfl_xor(aZ, 32);
        aN += __shfl_xor(aN, 16); aN += __shfl_xor(aN, 32);

        // ---- gates fully in-register (lane l<16 owns h[wid*16+l]) ----
        if (lane < 16) {
            float xr = gR + birL + aR;
            float xz = gZ + bizL + aZ;
            float xn = gN + binnL;
            float r = 1.f / (1.f + __expf(-xr));
            float z = 1.f / (1.f + __expf(-xz));
            float targ = xn + r * (aN + bnnL);
            float e2 = __expf(2.f * targ);
            float n = 1.f - 2.f / (e2 + 1.f);
            hreg = (1.f - z) * n + z * hreg;
            _Float16 hh = (_Float16)hreg;
            // h-index j = wid*16+lane -> quarter q=wid>>2, dword q*36+(j&63)/2
            int di = (wid >> 2) * 36 + (wid & 3) * 8 + (lane >> 1);
            ((u16*)&sH2[(p + 1) & 1][0])[di * 2 + (lane & 1)] = __builtin_bit_cast(u16, hh);
        }
        __syncthreads();
    }

    // ---------------- MLP tail ----------------
    if (lane < 16) sHf[wid * 16 + lane] = hreg;
    __syncthreads();
    u32* sHid = (u32*)sG;             // 133 dwords
    u16* sL1 = (u16*)(sG + 512);      // 512 halves
    u16* sL2 = (u16*)(sG + 1024);     // 512 halves
    if (tid < 128) sHid[tid] = pack2(sHf[2 * tid], sHf[2 * tid + 1]);
    else if (tid < 132) { int i = tid - 128; sHid[tid] = pack2(sMisc[2 * i], sMisc[2 * i + 1]); }
    else if (tid == 132) sHid[132] = pack2(sMisc[8], 0.f);
    __syncthreads();
    // L1: 512 outputs (2 critics x 256)
    if (tid < 512) {
        int c = tid >> 8, o = tid & 255;
        float acc = b1[c * 256 + o];
        const u32* wp = ws + OFF_W1 + c * 133 * 256 + o;
        #pragma unroll 4
        for (int kk = 0; kk < 133; ++kk) acc = fdot2(wp[kk * 256], sHid[kk], acc);
        acc = fmaxf(acc, 0.f);
        _Float16 a16 = (_Float16)acc;
        sL1[tid] = __builtin_bit_cast(u16, a16);
    }
    __syncthreads();
    // L2
    if (tid < 512) {
        int c = tid >> 8, o = tid & 255;
        float acc = b2[c * 256 + o];
        const u32* wp = ws + OFF_W2 + c * 128 * 256 + o;
        const u32* hp = (const u32*)sL1 + c * 128;
        #pragma unroll 4
        for (int kk = 0; kk < 128; ++kk) acc = fdot2(wp[kk * 256], hp[kk], acc);
        acc = fmaxf(acc, 0.f);
        _Float16 a16 = (_Float16)acc;
        sL2[tid] = __builtin_bit_cast(u16, a16);
    }
    __syncthreads();
    // L3: 2 outputs via wave reduction
    if (tid < 128) {
        int c = tid >> 6, l = tid & 63;
        const u32* wp = ws + OFF_W3 + c * 128;
        const u32* hp = (const u32*)sL2 + c * 128;
        float acc = fdot2(wp[l], hp[l], 0.f);
        acc = fdot2(wp[64 + l], hp[64 + l], acc);
        #pragma unroll
        for (int off = 32; off > 0; off >>= 1) acc += __shfl_down(acc, off);
        if (l == 0) out[b * 2 + c] = acc + b3[c];
    }
}

extern "C" void kernel_launch(void* const* d_in, const int* in_sizes, int n_in,
                              void* d_out, int out_size, void* d_ws, size_t ws_size,
                              hipStream_t stream) {
    const float* particles = (const float*)d_in[0];
    const float* pweights  = (const float*)d_in[1];
    const float* actions   = (const float*)d_in[2];
    const float* timev     = (const float*)d_in[3];
    const float* Wi        = (const float*)d_in[4];
    const float* bi        = (const float*)d_in[5];
    const float* Whrz      = (const float*)d_in[6];
    const float* Whn       = (const float*)d_in[7];
    const float* bn        = (const float*)d_in[8];
    const float* W1        = (const float*)d_in[9];
    const float* b1        = (const float*)d_in[10];
    const float* W2        = (const float*)d_in[11];
    const float* b2        = (const float*)d_in[12];
    const float* W3        = (const float*)d_in[13];
    const float* b3        = (const float*)d_in[14];
    const int*   nts       = (const int*)d_in[15];
    u32* ws = (u32*)d_ws;
    float* outp = (float*)d_out;

    pack_kernel<<<(WS_DWORDS + 255) / 256, 256, 0, stream>>>(Wi, Whrz, Whn, W1, W2, W3, ws);
    qnet_kernel<<<NB, NT, 0, stream>>>(particles, pweights, actions, timev,
                                       bi, bn, b1, b2, b3, nts, ws, outp);
}